// Round 3
// baseline (30.510 us; speedup 1.0000x reference)
//
#include <hip/hip_runtime.h>

#define CP_NUM 16
#define SEGS   16
#define WPB    4            // waves (= curves) per block
#define BLK    (WPB * 64)

typedef float f32x4 __attribute__((ext_vector_type(4)));

// One WAVE per curve. Setup is pure register/shuffle dataflow (no LDS until
// the final coefficient table), then 8 coalesced nontemporal float4 stores
// per lane.
//   A. lanes load aux control points directly from global (lane i -> aux[i])
//   B. centripetal knot increments + 5-step shuffle inclusive scan
//   C. lanes 0..15 expand Barry-Goldman to cubic coeffs in s = tv - t1,
//      write 12-float records to LDS (only LDS use in the kernel)
//   D. all lanes emit 8 float4 via Horner; coeff reads are half-wave
//      LDS broadcasts (conflict-free)
__global__ __launch_bounds__(BLK) void spline_poly_kernel(
    const float* __restrict__ cps, float* __restrict__ out, int nb)
{
    __shared__ __align__(16) float s_seg[WPB][SEGS][12]; // cx[4] cy[4] dt pad[3]

    const int lane = threadIdx.x & 63;
    const int wv   = threadIdx.x >> 6;
    const int b    = blockIdx.x * WPB + wv;
    if (b >= nb) return;

    const float* cpb = cps + (size_t)b * (CP_NUM * 2);

    // ---- Phase A: aux points in registers, lane i holds aux[i] (i<19) ----
    // aux[1..16] = cps[0..15], aux[17] = cps[0]; aux[0], aux[18] derived.
    const int src = (lane - 1) & 15;            // lane 17 -> 0, lanes 1..16 -> 0..15
    const float2 ld = *reinterpret_cast<const float2*>(cpb + src * 2);
    const float c0x = __shfl(ld.x, 1),  c0y = __shfl(ld.y, 1);   // cps[0]
    const float c1x = __shfl(ld.x, 2),  c1y = __shfl(ld.y, 2);   // cps[1]
    const float cLx = __shfl(ld.x, 16), cLy = __shfl(ld.y, 16);  // cps[15]

    const float dx01 = c0x - c1x, dy01 = c0y - c1y;
    const float l01   = sqrtf(dx01 * dx01 + dy01 * dy01 + 1e-7f);
    const float dxl = c0x - cLx, dyl = c0y - cLy;                // cc[-1]-cc[-2]
    const float llast = sqrtf(dxl * dxl + dyl * dyl + 1e-7f);

    float ax = ld.x, ay = ld.y;
    if (lane == 0) {
        const float r = l01 / llast;
        ax = c0x - r * dxl;  ay = c0y - r * dyl;
    } else if (lane == 18) {
        const float r = llast / l01;
        ax = c0x + r * (c1x - c0x);  ay = c0y + r * (c1y - c0y);
    }

    // ---- Phase B: knot increments + wave inclusive scan (t[l+1] in lane l) --
    const float nax = __shfl(ax, lane + 1);
    const float nay = __shfl(ay, lane + 1);
    float len = 0.f;
    if (lane < 18) {
        const float dx = nax - ax, dy = nay - ay;
        len = sqrtf(sqrtf(dx * dx + dy * dy));   // (||d||^2)^(1/4)
    }
    #pragma unroll
    for (int d = 1; d < 32; d <<= 1) {
        const float n = __shfl_up(len, d);
        if (lane >= d) len += n;
    }

    // ---- Phase C: cubic coefficients per segment (lanes 0..15) ----
    const float tm1 = __shfl(len, (lane - 1) & 63);
    const float t0  = (lane == 0) ? 0.f : tm1;
    const float t1  = len;
    const float t2  = __shfl(len, lane + 1);
    const float t3  = __shfl(len, lane + 2);
    const float p1x = nax,                  p1y = nay;
    const float p2x = __shfl(ax, lane + 2), p2y = __shfl(ay, lane + 2);
    const float p3x = __shfl(ax, lane + 3), p3y = __shfl(ay, lane + 3);

    if (lane < SEGS) {
        const float A  = t1 - t0, Bk = t2 - t1, C = t3 - t2;
        const float BC = Bk + C;
        const float r10 = 1.f / A;
        const float r21 = 1.f / Bk;
        const float r32 = 1.f / C;
        const float r20 = 1.f / (A + Bk);
        const float r31 = 1.f / BC;

        float* sp = s_seg[wv][lane];
        #pragma unroll
        for (int d = 0; d < 2; ++d) {   // d=0: x, d=1: y
            const float P0 = d ? ay  : ax;
            const float P1 = d ? p1y : p1x;
            const float P2 = d ? p2y : p2x;
            const float P3 = d ? p3y : p3x;
            // Linear pyramid legs: value + slope in s = tv - t1
            const float L1c0 = P1,                        L1c1 = (P1 - P0) * r10;
            const float L2c0 = P1,                        L2c1 = (P2 - P1) * r21;
            const float L3c0 = (BC * P2 - Bk * P3) * r32, L3c1 = (P3 - P2) * r32;
            // Quadratics
            const float Q1c0 = r20 * (Bk * L1c0 + A * L2c0);
            const float Q1c1 = r20 * (Bk * L1c1 - L1c0 + A * L2c1 + L2c0);
            const float Q1c2 = r20 * (L2c1 - L1c1);
            const float Q2c0 = r31 * (BC * L2c0);
            const float Q2c1 = r31 * (BC * L2c1 - L2c0 + L3c0);
            const float Q2c2 = r31 * (L3c1 - L2c1);
            // Cubic: [1,-r21] conv Q1 + [0,r21] conv Q2
            sp[d * 4 + 0] = Q1c0;
            sp[d * 4 + 1] = Q1c1 + r21 * (Q2c0 - Q1c0);
            sp[d * 4 + 2] = Q1c2 + r21 * (Q2c1 - Q1c1);
            sp[d * 4 + 3] = r21 * (Q2c2 - Q1c2);
        }
        sp[8] = Bk;   // t2 - t1: scales u into local parameter s
    }
    __builtin_amdgcn_wave_barrier();

    // ---- Phase D: emit 1024 points = 512 float4, coalesced nt stores ----
    // f = lane + 64*i:  f&31 == lane&31 (loop-invariant), seg = 2*i + (lane>=32).
    f32x4* outw = reinterpret_cast<f32x4*>(out + (size_t)b * (SEGS * 64 * 2));
    const int   hi = lane >> 5;
    const float q0 = (float)((lane & 31) * 2)     * (1.f / 63.f);
    const float q1 = (float)((lane & 31) * 2 + 1) * (1.f / 63.f);
    #pragma unroll
    for (int i = 0; i < 8; ++i) {
        const float* sp = s_seg[wv][2 * i + hi];
        const f32x4 cx = *reinterpret_cast<const f32x4*>(sp);
        const f32x4 cy = *reinterpret_cast<const f32x4*>(sp + 4);
        const float dt = sp[8];
        const float s0 = dt * q0;
        const float s1 = dt * q1;
        f32x4 o;
        o.x = ((cx.w * s0 + cx.z) * s0 + cx.y) * s0 + cx.x;
        o.y = ((cy.w * s0 + cy.z) * s0 + cy.y) * s0 + cy.x;
        o.z = ((cx.w * s1 + cx.z) * s1 + cx.y) * s1 + cx.x;
        o.w = ((cy.w * s1 + cy.z) * s1 + cy.y) * s1 + cy.x;
        __builtin_nontemporal_store(o, &outw[lane + 64 * i]);
    }
}

extern "C" void kernel_launch(void* const* d_in, const int* in_sizes, int n_in,
                              void* d_out, int out_size, void* d_ws, size_t ws_size,
                              hipStream_t stream) {
    const float* cps = (const float*)d_in[0];
    float* out = (float*)d_out;
    const int B = in_sizes[0] / (CP_NUM * 2);          // 16384
    const int grid = (B + WPB - 1) / WPB;              // 4096
    spline_poly_kernel<<<grid, BLK, 0, stream>>>(cps, out, B);
}

// Round 4
// 27.879 us; speedup vs baseline: 1.0944x; 1.0944x over previous
//
#include <hip/hip_runtime.h>

#define CP_NUM 16
#define SEGS   16
#define WPB    4            // waves (= curves) per block
#define BLK    (WPB * 64)

typedef float f32x4 __attribute__((ext_vector_type(4)));

// Fast reciprocal: v_rcp_f32 (~1 ulp) — precision is ample for the 9.25e-2
// absmax threshold (measured absmax with precise divides: 1.56e-2).
__device__ __forceinline__ float frcp(float x) { return __builtin_amdgcn_rcpf(x); }

// One block per 4 curves, one WAVE per curve for emit. Structure identical to
// the round-2 kernel (best so far); divides replaced with v_rcp_f32 and
// occupancy pinned to 8 blocks/CU.
__global__ __launch_bounds__(BLK, 8) void spline_poly_kernel(
    const float* __restrict__ cps, float* __restrict__ out, int nb)
{
    __shared__ __align__(16) float s_cp [WPB][CP_NUM * 2];
    __shared__ __align__(16) float s_aux[WPB][19 * 2];
    __shared__ __align__(16) float s_t  [WPB][20];
    __shared__ __align__(16) float s_seg[WPB][SEGS][12]; // cx[4] cy[4] dt pad[3]

    const int lane = threadIdx.x & 63;
    const int wv   = threadIdx.x >> 6;
    const int b    = blockIdx.x * WPB + wv;
    if (b >= nb) return;

    // ---- Phase 1: stage control points (8 x float4, coalesced) ----
    if (lane < 8) {
        reinterpret_cast<float4*>(s_cp[wv])[lane] =
            reinterpret_cast<const float4*>(cps + (size_t)b * (CP_NUM * 2))[lane];
    }
    __builtin_amdgcn_wave_barrier();

    // ---- Phase 2: auxiliary points ----
    // aux[0]=aux_first, aux[1..16]=cps[0..15], aux[17]=cps[0], aux[18]=aux_last
    if (lane < 19) {
        const float c0x = s_cp[wv][0],  c0y = s_cp[wv][1];
        const float c1x = s_cp[wv][2],  c1y = s_cp[wv][3];
        const float cLx = s_cp[wv][30], cLy = s_cp[wv][31];
        const float dx01 = c0x - c1x, dy01 = c0y - c1y;
        const float l01   = sqrtf(dx01 * dx01 + dy01 * dy01 + 1e-7f);
        const float dxl = c0x - cLx, dyl = c0y - cLy;     // cc[-1]-cc[-2]
        const float llast = sqrtf(dxl * dxl + dyl * dyl + 1e-7f);
        float ax, ay;
        if (lane == 0) {
            const float r = l01 * frcp(llast);
            ax = c0x - r * dxl;  ay = c0y - r * dyl;
        } else if (lane <= CP_NUM) {
            ax = s_cp[wv][(lane - 1) * 2];  ay = s_cp[wv][(lane - 1) * 2 + 1];
        } else if (lane == CP_NUM + 1) {
            ax = c0x;  ay = c0y;
        } else {
            const float r = llast * frcp(l01);
            ax = c0x + r * (c1x - c0x);  ay = c0y + r * (c1y - c0y);
        }
        s_aux[wv][lane * 2]     = ax;
        s_aux[wv][lane * 2 + 1] = ay;
    }
    __builtin_amdgcn_wave_barrier();

    // ---- Phase 3: knot increments + wave inclusive scan ----
    float len = 0.f;
    if (lane < 18) {
        const float dx = s_aux[wv][(lane + 1) * 2]     - s_aux[wv][lane * 2];
        const float dy = s_aux[wv][(lane + 1) * 2 + 1] - s_aux[wv][lane * 2 + 1];
        len = sqrtf(sqrtf(dx * dx + dy * dy));   // (||d||^2)^(1/4)
    }
    #pragma unroll
    for (int d = 1; d < 32; d <<= 1) {
        const float n = __shfl_up(len, d);
        if (lane >= d) len += n;
    }
    if (lane == 0) s_t[wv][0] = 0.f;
    if (lane < 18) s_t[wv][lane + 1] = len;
    __builtin_amdgcn_wave_barrier();

    // ---- Phase 4: cubic coefficients per segment (lanes 0..15) ----
    if (lane < SEGS) {
        const float t0 = s_t[wv][lane];
        const float t1 = s_t[wv][lane + 1];
        const float t2 = s_t[wv][lane + 2];
        const float t3 = s_t[wv][lane + 3];
        const float A  = t1 - t0, Bk = t2 - t1, C = t3 - t2;
        const float BC = Bk + C;
        const float r10 = frcp(A);
        const float r21 = frcp(Bk);
        const float r32 = frcp(C);
        const float r20 = frcp(A + Bk);
        const float r31 = frcp(BC);

        float* sp = s_seg[wv][lane];
        #pragma unroll
        for (int d = 0; d < 2; ++d) {   // d=0: x, d=1: y
            const float P0 = s_aux[wv][lane * 2 + d];
            const float P1 = s_aux[wv][lane * 2 + 2 + d];
            const float P2 = s_aux[wv][lane * 2 + 4 + d];
            const float P3 = s_aux[wv][lane * 2 + 6 + d];
            // Linear pyramid legs: value + slope in s = tv - t1
            const float L1c0 = P1,                        L1c1 = (P1 - P0) * r10;
            const float L2c0 = P1,                        L2c1 = (P2 - P1) * r21;
            const float L3c0 = (BC * P2 - Bk * P3) * r32, L3c1 = (P3 - P2) * r32;
            // Quadratics
            const float Q1c0 = r20 * (Bk * L1c0 + A * L2c0);
            const float Q1c1 = r20 * (Bk * L1c1 - L1c0 + A * L2c1 + L2c0);
            const float Q1c2 = r20 * (L2c1 - L1c1);
            const float Q2c0 = r31 * (BC * L2c0);
            const float Q2c1 = r31 * (BC * L2c1 - L2c0 + L3c0);
            const float Q2c2 = r31 * (L3c1 - L2c1);
            // Cubic: [1,-r21] conv Q1 + [0,r21] conv Q2
            sp[d * 4 + 0] = Q1c0;
            sp[d * 4 + 1] = Q1c1 + r21 * (Q2c0 - Q1c0);
            sp[d * 4 + 2] = Q1c2 + r21 * (Q2c1 - Q1c1);
            sp[d * 4 + 3] = r21 * (Q2c2 - Q1c2);
        }
        sp[8] = Bk;   // t2 - t1: scales u into local parameter s
    }
    __builtin_amdgcn_wave_barrier();

    // ---- Phase 5: emit 1024 points = 512 float4, coalesced ----
    // f = lane + 64*i: f&31 == lane&31 (loop-invariant), seg = 2*i + (lane>=32).
    f32x4* outw = reinterpret_cast<f32x4*>(out + (size_t)b * (SEGS * 64 * 2));
    const int   hi = lane >> 5;
    const float q0 = (float)((lane & 31) * 2)     * (1.f / 63.f);
    const float q1 = (float)((lane & 31) * 2 + 1) * (1.f / 63.f);
    #pragma unroll
    for (int i = 0; i < 8; ++i) {
        const float* sp = s_seg[wv][2 * i + hi];
        const f32x4 cx = *reinterpret_cast<const f32x4*>(sp);
        const f32x4 cy = *reinterpret_cast<const f32x4*>(sp + 4);
        const float dt = sp[8];
        const float s0 = dt * q0;
        const float s1 = dt * q1;
        f32x4 o;
        o.x = ((cx.w * s0 + cx.z) * s0 + cx.y) * s0 + cx.x;
        o.y = ((cy.w * s0 + cy.z) * s0 + cy.y) * s0 + cy.x;
        o.z = ((cx.w * s1 + cx.z) * s1 + cx.y) * s1 + cx.x;
        o.w = ((cy.w * s1 + cy.z) * s1 + cy.y) * s1 + cy.x;
        outw[lane + 64 * i] = o;
    }
}

extern "C" void kernel_launch(void* const* d_in, const int* in_sizes, int n_in,
                              void* d_out, int out_size, void* d_ws, size_t ws_size,
                              hipStream_t stream) {
    const float* cps = (const float*)d_in[0];
    float* out = (float*)d_out;
    const int B = in_sizes[0] / (CP_NUM * 2);          // 16384
    const int grid = (B + WPB - 1) / WPB;              // 4096
    spline_poly_kernel<<<grid, BLK, 0, stream>>>(cps, out, B);
}